// Round 10
// baseline (363.444 us; speedup 1.0000x reference)
//
#include <hip/hip_runtime.h>
#include <hip/hip_fp16.h>

// SparseGraphWaveletLayer: out = relu( (phi·diag(theta)) @ (phi_inv @ (F_sparse @ W)) )
// N=50000, IN_CH=256, OUT_CH=128, NNZ=800000 per sparse matrix.
//
// Round 22 -> 23: revert the dual-row SpMM (215.5us, co-loop overlap fails on
// unequal row lengths) to the round-21 single-row unroll-16 (206.2us best).
// One new delta: phase D pads every CSR row to a multiple of 4 edges with
// zero-valued edges (col=0, val=0 -> exact FMA no-ops) and 4-aligns bucket
// bases, so every off[r] is 16B-aligned and the SpMM edge stream is read
// with dwordx4 (4 loads/16-edge iter instead of 16 scalar dwords; no scalar
// tail). ec grows ~9% (zeros). eb/C layout and all other phases identical
// to round 21.

#define OUT_CH 128
#define HALF_CH 64
#define RPB 256           // rows per bucket
#define RPB_SHIFT 8
#define MAX_NB 256        // supports N <= 65536
#define EPB 4096          // edges per block in phases A/C
#define EPT_C 8           // edges per thread in phase C (512 thr)
#define EPT_D 16          // edges per thread in phase D (512 thr x 16 = 8192)
#define STAGE_CAP_P 9216  // phase-D LDS staging capacity (36KB of u32, padded)
#define PAD_SLACK 1024    // per-bucket padded-layout slack (256 rows x 3 + align)
#define MAX_INCH_LDS 256  // W-in-LDS guard: in_ch*64 half2 <= 64KB

// ---------------- Phase A: per-block bucket histograms ----------------------

__global__ __launch_bounds__(512) void bucket_hist_kernel(
    const int* __restrict__ rows0, int n0,
    const int* __restrict__ rows1, int n1,
    const int* __restrict__ rows2, int n2,
    int* __restrict__ hist_part,        // [3][NBLK][NB]
    int NB, int NBLK)
{
    int m = blockIdx.y;
    const int* rows = (m == 0) ? rows0 : (m == 1) ? rows1 : rows2;
    int nnz         = (m == 0) ? n0    : (m == 1) ? n1    : n2;
    __shared__ int bins[MAX_NB];
    int t = threadIdx.x;
    if (t < NB) bins[t] = 0;
    __syncthreads();
    int base = blockIdx.x * EPB;
    #pragma unroll
    for (int k = 0; k < EPB / 512; ++k) {
        int i = base + k * 512 + t;
        if (i < nnz) atomicAdd(&bins[rows[i] >> RPB_SHIFT], 1);
    }
    __syncthreads();
    int* out = hist_part + ((size_t)(m * NBLK + blockIdx.x)) * NB;
    if (t < NB) out[t] = bins[t];
}

// ---------------- Phase B1: wave-per-(m,bucket) totals reduction ------------

__global__ __launch_bounds__(256) void reduce_totals_kernel(
    const int* __restrict__ hist_part, int* __restrict__ totals, int NB, int NBLK)
{
    int w = blockIdx.x * 4 + (threadIdx.x >> 6);
    if (w >= 3 * NB) return;
    int lane = threadIdx.x & 63;
    int m = w / NB, b = w - m * NB;
    const int* hp = hist_part + (size_t)m * NBLK * NB + b;
    int sum = 0;
    for (int blk = lane; blk < NBLK; blk += 64)
        sum += hp[(size_t)blk * NB];
    #pragma unroll
    for (int s = 1; s < 64; s <<= 1) sum += __shfl_xor(sum, s);
    if (lane == 0) totals[w] = sum;
}

// ---------------- Phase B2: scan totals -> bases + cursors ------------------

__global__ __launch_bounds__(256) void scan_bases_kernel(
    const int* __restrict__ totals, int* __restrict__ bases,
    int* __restrict__ cursor, int NB)
{
    int m = blockIdx.x, t = threadIdx.x;
    int x = (t < NB) ? totals[m * NB + t] : 0;
    int lane = t & 63, wid = t >> 6;
    int incl = x;
    #pragma unroll
    for (int s = 1; s < 64; s <<= 1) {
        int y = __shfl_up(incl, s);
        if (lane >= s) incl += y;
    }
    __shared__ int wtot[4], wbase[4];
    if (lane == 63) wtot[wid] = incl;
    __syncthreads();
    if (t == 0) {
        int run = 0;
        #pragma unroll
        for (int w = 0; w < 4; ++w) { int v = wtot[w]; wbase[w] = run; run += v; }
    }
    __syncthreads();
    if (t < NB) {
        int excl = wbase[wid] + incl - x;
        bases[m * NB + t] = excl;
        cursor[m * NB + t] = excl;
    }
}

// ---------------- Phase C: LDS-staged bucket scatter (chunk-claiming) -------

__global__ __launch_bounds__(512) void bucket_scatter_kernel(
    const int* __restrict__ rows0, const int* __restrict__ cols0, const float* __restrict__ vals0, int n0,
    const int* __restrict__ rows1, const int* __restrict__ cols1, const float* __restrict__ vals1, int n1,
    const int* __restrict__ rows2, const int* __restrict__ cols2, const float* __restrict__ vals2, int n2,
    const float* __restrict__ theta,
    const int* __restrict__ hist_part, int* __restrict__ cursor,
    int2* __restrict__ eb0, int2* __restrict__ eb1, int2* __restrict__ eb2,
    int NB, int NBLK)
{
    int m = blockIdx.y;
    const int* rows; const int* cols; const float* vals; int nnz; int2* eb;
    if (m == 0)      { rows = rows0; cols = cols0; vals = vals0; nnz = n0; eb = eb0; }
    else if (m == 1) { rows = rows1; cols = cols1; vals = vals1; nnz = n1; eb = eb1; }
    else             { rows = rows2; cols = cols2; vals = vals2; nnz = n2; eb = eb2; }

    __shared__ int2 staged[EPB];               // 32 KB
    __shared__ unsigned char bucket_of[EPB];   // 4 KB
    __shared__ int lstart[MAX_NB];
    __shared__ int lcur[MAX_NB];
    __shared__ int gbase[MAX_NB];
    __shared__ int wtot[8], wbase[8];

    int t = threadIdx.x;
    int base = blockIdx.x * EPB;
    bool fold = (m == 2);

    // load edges into registers
    int  bk[EPT_C];
    int2 pl[EPT_C];
    #pragma unroll
    for (int k = 0; k < EPT_C; ++k) {
        int i = base + k * 512 + t;
        if (i < nnz) {
            int r = rows[i], c = cols[i];
            float v = vals[i];
            if (fold) v *= theta[c];
            bk[k] = r >> RPB_SHIFT;
            pl[k] = make_int2(c | ((r & (RPB - 1)) << 16), __float_as_int(v));
        } else bk[k] = -1;
    }

    {   // per-block histogram comes precomputed from phase A; 8-wave scan
        const int* hp = hist_part + ((size_t)(m * NBLK + blockIdx.x)) * NB;
        int lh = (t < NB) ? hp[t] : 0;
        int lane = t & 63, wid = t >> 6;
        int incl = lh;
        #pragma unroll
        for (int s = 1; s < 64; s <<= 1) {
            int y = __shfl_up(incl, s);
            if (lane >= s) incl += y;
        }
        if (lane == 63) wtot[wid] = incl;
        __syncthreads();
        if (t == 0) {
            int run = 0;
            #pragma unroll
            for (int w = 0; w < 8; ++w) { int v = wtot[w]; wbase[w] = run; run += v; }
        }
        __syncthreads();
        if (t < NB) {
            int excl = wbase[wid] + incl - lh;
            lstart[t] = excl;
            lcur[t]   = excl;
            // claim a contiguous chunk of the bucket's output range
            gbase[t] = atomicAdd(&cursor[m * NB + t], lh);
        }
    }
    __syncthreads();

    #pragma unroll
    for (int k = 0; k < EPT_C; ++k) {
        if (bk[k] >= 0) {
            int idx = atomicAdd(&lcur[bk[k]], 1);     // LDS atomic
            staged[idx] = pl[k];
            bucket_of[idx] = (unsigned char)bk[k];
        }
    }
    __syncthreads();

    int count = min(EPB, nnz - base);
    for (int i = t; i < count; i += 512) {
        int b = bucket_of[i];
        int dest = gbase[b] + (i - lstart[b]);
        eb[dest] = staged[i];
    }
}

// ---------------- Phase D: bucket -> row-sorted PADDED compressed CSR -------
// Register-staged as in round 21. New: per-row edge counts are padded up to
// multiples of 4 (zero edges: col=0, val=0) and bucket bases 4-aligned, so
// every off[r] is a multiple of 4 (16B-aligned edge stream). Gaps between a
// bucket's padded end and the next bucket's padded base are zero-filled.

__global__ __launch_bounds__(512) void bucket_to_csr_kernel(
    const int2* __restrict__ eb0, const int2* __restrict__ eb1, const int2* __restrict__ eb2,
    unsigned int* __restrict__ ec0, unsigned int* __restrict__ ec1, unsigned int* __restrict__ ec2,
    const int* __restrict__ bases,
    int* __restrict__ off,              // [3][n+1]
    int n0, int n1, int n2, int NB, int n)
{
    int m = blockIdx.y;
    int b = blockIdx.x;
    const int2* eb; unsigned int* ec; int nnz;
    if (m == 0)      { eb = eb0; ec = ec0; nnz = n0; }
    else if (m == 1) { eb = eb1; ec = ec1; nnz = n1; }
    else             { eb = eb2; ec = ec2; nnz = n2; }
    int base  = bases[m * NB + b];
    int nextb = (b + 1 < NB) ? bases[m * NB + b + 1] : nnz;
    int end   = nextb;
    int cnt   = end - base;
    int pbase = ((base  + 3) & ~3) + b * PAD_SLACK;
    int pnext = ((nextb + 3) & ~3) + (b + 1) * PAD_SLACK;

    __shared__ unsigned int staged_c[STAGE_CAP_P];   // 36 KB
    __shared__ int hist[RPB];
    __shared__ int cur[RPB];
    __shared__ int loc[RPB + 1];
    __shared__ int wtot[4];
    __shared__ int wbase[4];
    int t = threadIdx.x;
    int lane = t & 63, wid = t >> 6;
    if (t < RPB) { hist[t] = 0; cur[t] = 0; }
    __syncthreads();

    bool fits = (cnt <= EPT_D * 512);

    // ---- pass 1: row histogram ----
    int2 er[EPT_D];
    int  rl[EPT_D];
    if (fits) {
        #pragma unroll
        for (int k = 0; k < EPT_D; ++k) {
            int i = base + k * 512 + t;
            if (i < end) {
                er[k] = eb[i];
                rl[k] = (er[k].x >> 16) & (RPB - 1);
                atomicAdd(&hist[rl[k]], 1);
            } else rl[k] = -1;
        }
    } else {
        for (int i = base + t; i < end; i += 512)
            atomicAdd(&hist[(eb[i].x >> 16) & (RPB - 1)], 1);
    }
    __syncthreads();

    {   // exclusive scan of PADDED (ceil4) counts (first 4 waves produce)
        int x = (t < RPB) ? ((hist[t] + 3) & ~3) : 0;
        int incl = x;
        #pragma unroll
        for (int s = 1; s < 64; s <<= 1) {
            int y = __shfl_up(incl, s);
            if (lane >= s) incl += y;
        }
        if (lane == 63 && wid < 4) wtot[wid] = incl;
        __syncthreads();
        if (t == 0) {
            int run = 0;
            #pragma unroll
            for (int w = 0; w < 4; ++w) { int v = wtot[w]; wbase[w] = run; run += v; }
        }
        __syncthreads();
        if (t < RPB) {
            loc[t] = wbase[wid] + incl - x;
            if (t == RPB - 1) loc[RPB] = wbase[3] + incl;
        }
    }
    __syncthreads();
    if (t < RPB) {
        int r = b * RPB + t;
        if (r < n) off[(size_t)m * (n + 1) + r] = pbase + loc[t];
    }
    if (b == NB - 1 && t == 0) off[(size_t)m * (n + 1) + n] = pnext;
    int totp = loc[RPB];

    // ---- pass 2: row-sorted scatter (padded slots pre-zeroed) ----
    if (fits) {
        for (int i = t; i < totp; i += 512) staged_c[i] = 0;
        __syncthreads();
        #pragma unroll
        for (int k = 0; k < EPT_D; ++k) {
            if (rl[k] >= 0) {
                int rk = atomicAdd(&cur[rl[k]], 1);   // LDS atomic
                unsigned short h = __half_as_ushort(__float2half_rn(__int_as_float(er[k].y)));
                staged_c[loc[rl[k]] + rk] = (unsigned int)(er[k].x & 0xFFFF) | ((unsigned int)h << 16);
            }
        }
        __syncthreads();
        for (int i = t; i < totp; i += 512)
            ec[pbase + i] = staged_c[i];
        for (int i = pbase + totp + t; i < pnext; i += 512)
            ec[i] = 0;
    } else {
        // oversized bucket: direct scatter + explicit pad zeroing
        for (int i = base + t; i < end; i += 512) {
            int2 e = eb[i];
            int r2 = (e.x >> 16) & (RPB - 1);
            int rk = atomicAdd(&cur[r2], 1);
            unsigned short h = __half_as_ushort(__float2half_rn(__int_as_float(e.y)));
            ec[pbase + loc[r2] + rk] = (unsigned int)(e.x & 0xFFFF) | ((unsigned int)h << 16);
        }
        __syncthreads();
        if (t < RPB) {
            int s0 = loc[t] + hist[t];
            int e0 = loc[t] + ((hist[t] + 3) & ~3);
            for (int i = s0; i < e0; ++i) ec[pbase + i] = 0;
        }
        for (int i = pbase + totp + t; i < pnext; i += 512)
            ec[i] = 0;
    }
}

// ---------------- stage-1 SpMM with W resident in LDS -----------------------

__global__ __launch_bounds__(1024) void spmm_w_lds_kernel(
    const int* __restrict__ off, const unsigned int* __restrict__ edges,
    const float* __restrict__ W, __half2* __restrict__ out,
    int nrows, int in_ch)
{
    __shared__ __half2 wlds[MAX_INCH_LDS * HALF_CH];   // 64 KB
    int t = threadIdx.x;
    {   // stage W -> LDS (fp32 -> fp16), coalesced float2 reads
        const float2* wf = (const float2*)W;
        int tot = in_ch * HALF_CH;
        for (int i = t; i < tot; i += 1024) {
            float2 f = wf[i];
            wlds[i] = __float22half2_rn(f);
        }
    }
    __syncthreads();

    int lane = t & 63, w = t >> 6;     // 16 waves
    #pragma unroll
    for (int k4 = 0; k4 < 4; ++k4) {
        int r = blockIdx.x * 64 + k4 * 16 + w;
        if (r >= nrows) continue;
        int j   = __builtin_amdgcn_readfirstlane(off[r]);
        int end = __builtin_amdgcn_readfirstlane(off[r + 1]);
        float2 a0 = make_float2(0.f, 0.f), a1 = make_float2(0.f, 0.f);

        for (; j + 16 <= end; j += 16) {
            uint4 q0 = *(const uint4*)(edges + j);
            uint4 q1 = *(const uint4*)(edges + j + 4);
            uint4 q2 = *(const uint4*)(edges + j + 8);
            uint4 q3 = *(const uint4*)(edges + j + 12);
            unsigned int e[16] = {q0.x,q0.y,q0.z,q0.w, q1.x,q1.y,q1.z,q1.w,
                                  q2.x,q2.y,q2.z,q2.w, q3.x,q3.y,q3.z,q3.w};
            #pragma unroll
            for (int k = 0; k < 16; ++k) {
                float2 d = __half22float2(wlds[(e[k] & 0xFFFF) * HALF_CH + lane]);
                float v = __half2float(__ushort_as_half((unsigned short)(e[k] >> 16)));
                if (k & 1) { a1.x = fmaf(v, d.x, a1.x); a1.y = fmaf(v, d.y, a1.y); }
                else       { a0.x = fmaf(v, d.x, a0.x); a0.y = fmaf(v, d.y, a0.y); }
            }
        }
        for (; j + 4 <= end; j += 4) {
            uint4 q = *(const uint4*)(edges + j);
            unsigned int e[4] = {q.x, q.y, q.z, q.w};
            #pragma unroll
            for (int k = 0; k < 4; ++k) {
                float2 d = __half22float2(wlds[(e[k] & 0xFFFF) * HALF_CH + lane]);
                float v = __half2float(__ushort_as_half((unsigned short)(e[k] >> 16)));
                if (k & 1) { a1.x = fmaf(v, d.x, a1.x); a1.y = fmaf(v, d.y, a1.y); }
                else       { a0.x = fmaf(v, d.x, a0.x); a0.y = fmaf(v, d.y, a0.y); }
            }
        }
        for (; j < end; ++j) {
            unsigned int e0 = edges[j];
            float2 d = __half22float2(wlds[(e0 & 0xFFFF) * HALF_CH + lane]);
            float v0 = __half2float(__ushort_as_half((unsigned short)(e0 >> 16)));
            a0.x = fmaf(v0, d.x, a0.x); a0.y = fmaf(v0, d.y, a0.y);
        }
        float2 res = make_float2(a0.x + a1.x, a0.y + a1.y);
        out[(size_t)r * HALF_CH + lane] = __float22half2_rn(res);
    }
}

// ---------------- gather-side CSR SpMM, dwordx4 edge loads, unroll-16 -------

template<bool SRC_H, bool DST_H, bool RELU>
__global__ __launch_bounds__(256) void spmm_csr_kernel(
    const int* __restrict__ off, const unsigned int* __restrict__ edges,
    const void* __restrict__ dense_v, void* __restrict__ out_v, int nrows)
{
    int lane = threadIdx.x & 63;
    int r = blockIdx.x * 4 + (threadIdx.x >> 6);
    if (r >= nrows) return;
    int j   = __builtin_amdgcn_readfirstlane(off[r]);
    int end = __builtin_amdgcn_readfirstlane(off[r + 1]);
    const float2*  df = (const float2*)dense_v;
    const __half2* dh = (const __half2*)dense_v;

    float2 a0 = make_float2(0.f, 0.f), a1 = make_float2(0.f, 0.f);

    for (; j + 16 <= end; j += 16) {
        uint4 q0 = *(const uint4*)(edges + j);
        uint4 q1 = *(const uint4*)(edges + j + 4);
        uint4 q2 = *(const uint4*)(edges + j + 8);
        uint4 q3 = *(const uint4*)(edges + j + 12);
        unsigned int e[16] = {q0.x,q0.y,q0.z,q0.w, q1.x,q1.y,q1.z,q1.w,
                              q2.x,q2.y,q2.z,q2.w, q3.x,q3.y,q3.z,q3.w};
        float2 d[16];
        #pragma unroll
        for (int k = 0; k < 16; ++k) {
            if (SRC_H) d[k] = __half22float2(dh[(size_t)(e[k] & 0xFFFF) * HALF_CH + lane]);
            else       d[k] = df[(size_t)(e[k] & 0xFFFF) * HALF_CH + lane];
        }
        #pragma unroll
        for (int k = 0; k < 16; ++k) {
            float v = __half2float(__ushort_as_half((unsigned short)(e[k] >> 16)));
            if (k & 1) { a1.x = fmaf(v, d[k].x, a1.x); a1.y = fmaf(v, d[k].y, a1.y); }
            else       { a0.x = fmaf(v, d[k].x, a0.x); a0.y = fmaf(v, d[k].y, a0.y); }
        }
    }
    for (; j + 8 <= end; j += 8) {
        uint4 q0 = *(const uint4*)(edges + j);
        uint4 q1 = *(const uint4*)(edges + j + 4);
        unsigned int e[8] = {q0.x,q0.y,q0.z,q0.w, q1.x,q1.y,q1.z,q1.w};
        float2 d[8];
        #pragma unroll
        for (int k = 0; k < 8; ++k) {
            if (SRC_H) d[k] = __half22float2(dh[(size_t)(e[k] & 0xFFFF) * HALF_CH + lane]);
            else       d[k] = df[(size_t)(e[k] & 0xFFFF) * HALF_CH + lane];
        }
        #pragma unroll
        for (int k = 0; k < 8; ++k) {
            float v = __half2float(__ushort_as_half((unsigned short)(e[k] >> 16)));
            if (k & 1) { a1.x = fmaf(v, d[k].x, a1.x); a1.y = fmaf(v, d[k].y, a1.y); }
            else       { a0.x = fmaf(v, d[k].x, a0.x); a0.y = fmaf(v, d[k].y, a0.y); }
        }
    }
    for (; j + 4 <= end; j += 4) {
        uint4 q = *(const uint4*)(edges + j);
        unsigned int e[4] = {q.x, q.y, q.z, q.w};
        float2 d[4];
        #pragma unroll
        for (int k = 0; k < 4; ++k) {
            if (SRC_H) d[k] = __half22float2(dh[(size_t)(e[k] & 0xFFFF) * HALF_CH + lane]);
            else       d[k] = df[(size_t)(e[k] & 0xFFFF) * HALF_CH + lane];
        }
        #pragma unroll
        for (int k = 0; k < 4; ++k) {
            float v = __half2float(__ushort_as_half((unsigned short)(e[k] >> 16)));
            if (k & 1) { a1.x = fmaf(v, d[k].x, a1.x); a1.y = fmaf(v, d[k].y, a1.y); }
            else       { a0.x = fmaf(v, d[k].x, a0.x); a0.y = fmaf(v, d[k].y, a0.y); }
        }
    }
    for (; j < end; ++j) {       // safety (rows are 4-padded; normally unreached)
        unsigned int e0 = edges[j];
        float2 d0;
        if (SRC_H) d0 = __half22float2(dh[(size_t)(e0 & 0xFFFF) * HALF_CH + lane]);
        else       d0 = df[(size_t)(e0 & 0xFFFF) * HALF_CH + lane];
        float v0 = __half2float(__ushort_as_half((unsigned short)(e0 >> 16)));
        a0.x = fmaf(v0, d0.x, a0.x); a0.y = fmaf(v0, d0.y, a0.y);
    }
    float2 res = make_float2(a0.x + a1.x, a0.y + a1.y);
    if (RELU) { res.x = fmaxf(res.x, 0.f); res.y = fmaxf(res.y, 0.f); }
    if (DST_H) ((__half2*)out_v)[(size_t)r * HALF_CH + lane] = __float22half2_rn(res);
    else       ((float2*) out_v)[(size_t)r * HALF_CH + lane] = res;
}

// ---------------- fallback (round-0) atomic path ----------------

__global__ __launch_bounds__(256) void spmm_atomic_kernel(
    const int* __restrict__ rows, const int* __restrict__ cols,
    const float* __restrict__ vals, const float* __restrict__ theta,
    const float* __restrict__ dense, float* __restrict__ out, int nnz)
{
    int idx = blockIdx.x * blockDim.x + threadIdx.x;
    int e = idx >> 7;
    int f = idx & (OUT_CH - 1);
    if (e >= nnz) return;
    int r = rows[e];
    int c = cols[e];
    float v = vals[e];
    if (theta != nullptr) v *= theta[c];
    atomicAdd(&out[(size_t)r * OUT_CH + f], v * dense[(size_t)c * OUT_CH + f]);
}

__global__ __launch_bounds__(256) void relu_kernel(float* __restrict__ out, int n4)
{
    int i = blockIdx.x * blockDim.x + threadIdx.x;
    if (i >= n4) return;
    float4 v = ((float4*)out)[i];
    v.x = fmaxf(v.x, 0.f); v.y = fmaxf(v.y, 0.f);
    v.z = fmaxf(v.z, 0.f); v.w = fmaxf(v.w, 0.f);
    ((float4*)out)[i] = v;
}

// ---------------- launch ----------------

static inline size_t align16(size_t x) { return (x + 15) & ~(size_t)15; }
static inline size_t pad_ec(int nnz, int NB) {
    return (size_t)(((nnz + 3) & ~3)) + (size_t)NB * PAD_SLACK + 16;
}

extern "C" void kernel_launch(void* const* d_in, const int* in_sizes, int n_in,
                              void* d_out, int out_size, void* d_ws, size_t ws_size,
                              hipStream_t stream)
{
    const int*   phi_idx   = (const int*)d_in[0];
    const float* phi_vals  = (const float*)d_in[1];
    const int*   phii_idx  = (const int*)d_in[2];
    const float* phii_vals = (const float*)d_in[3];
    const int*   feat_idx  = (const int*)d_in[4];
    const float* feat_vals = (const float*)d_in[5];
    const float* W         = (const float*)d_in[6];
    const float* theta     = (const float*)d_in[7];

    const int nnz_phi  = in_sizes[1];
    const int nnz_phii = in_sizes[3];
    const int nnz_feat = in_sizes[5];
    const int n_nodes  = in_sizes[7];
    const int in_ch    = in_sizes[6] / OUT_CH;
    const size_t dense_elems = (size_t)n_nodes * OUT_CH;
    const long long total_e = (long long)nnz_feat + nnz_phii + nnz_phi;

    const int NB = (n_nodes + RPB - 1) >> RPB_SHIFT;
    int max_nnz = nnz_feat > nnz_phii ? nnz_feat : nnz_phii;
    if (nnz_phi > max_nnz) max_nnz = nnz_phi;
    const int NBLK = (max_nnz + EPB - 1) / EPB;

    const size_t pec0 = pad_ec(nnz_feat, NB);
    const size_t pec1 = pad_ec(nnz_phii, NB);
    const size_t pec2 = pad_ec(nnz_phi,  NB);

    // ---- workspace layout ----
    size_t p = 0;
    size_t filtered_off = p; p += align16(dense_elems * sizeof(__half));
    size_t tmp_off      = p; p += align16(dense_elems * sizeof(__half));
    size_t off_off      = p; p += align16((size_t)3 * (n_nodes + 1) * sizeof(int));
    size_t hp_off       = p; p += align16((size_t)3 * NBLK * NB * sizeof(int));
    size_t tot_off      = p; p += align16((size_t)3 * NB * sizeof(int));
    size_t bas_off      = p; p += align16((size_t)3 * NB * sizeof(int));
    size_t cur_off      = p; p += align16((size_t)3 * NB * sizeof(int));
    size_t eb_off       = p; p += align16((size_t)total_e * sizeof(int2));
    size_t ec_off       = p; p += align16((pec0 + pec1 + pec2) * sizeof(unsigned int));
    size_t need = p;

    char* ws = (char*)d_ws;
    dim3 block256(256);
    dim3 block512(512);

    bool fast_ok = (ws_size >= need) && (NB <= MAX_NB) && (n_nodes <= 65536) &&
                   (in_ch <= 65536);

    if (fast_ok) {
        __half* filtered = (__half*)(ws + filtered_off);
        __half* tmp      = (__half*)(ws + tmp_off);
        int* off_arr    = (int*)(ws + off_off);
        int* hist_part  = (int*)(ws + hp_off);
        int* totals     = (int*)(ws + tot_off);
        int* bases      = (int*)(ws + bas_off);
        int* cursor     = (int*)(ws + cur_off);
        int2* eb0 = (int2*)(ws + eb_off);
        int2* eb1 = eb0 + nnz_feat;
        int2* eb2 = eb1 + nnz_phii;
        unsigned int* ec0 = (unsigned int*)(ws + ec_off);
        unsigned int* ec1 = ec0 + pec0;
        unsigned int* ec2 = ec1 + pec1;

        const int* rows0 = feat_idx;  const int* cols0 = feat_idx + nnz_feat;
        const int* rows1 = phii_idx;  const int* cols1 = phii_idx + nnz_phii;
        const int* rows2 = phi_idx;   const int* cols2 = phi_idx  + nnz_phi;

        bucket_hist_kernel<<<dim3(NBLK, 3), block512, 0, stream>>>(
            rows0, nnz_feat, rows1, nnz_phii, rows2, nnz_phi,
            hist_part, NB, NBLK);

        int nwaves = 3 * NB;
        reduce_totals_kernel<<<dim3((nwaves + 3) / 4), block256, 0, stream>>>(
            hist_part, totals, NB, NBLK);

        scan_bases_kernel<<<dim3(3), block256, 0, stream>>>(
            totals, bases, cursor, NB);

        bucket_scatter_kernel<<<dim3(NBLK, 3), block512, 0, stream>>>(
            rows0, cols0, feat_vals, nnz_feat,
            rows1, cols1, phii_vals, nnz_phii,
            rows2, cols2, phi_vals,  nnz_phi,
            theta, hist_part, cursor, eb0, eb1, eb2, NB, NBLK);

        bucket_to_csr_kernel<<<dim3(NB, 3), block512, 0, stream>>>(
            eb0, eb1, eb2, ec0, ec1, ec2, bases, off_arr,
            nnz_feat, nnz_phii, nnz_phi, NB, n_nodes);

        int* off_f  = off_arr;
        int* off_pi = off_arr + (n_nodes + 1);
        int* off_p  = off_arr + 2 * (n_nodes + 1);

        dim3 grid_r((unsigned)((n_nodes + 3) / 4));
        // stage 1: src fp32 W (LDS-resident fp16), dst fp16 filtered
        if (in_ch <= MAX_INCH_LDS) {
            dim3 grid_w((unsigned)((n_nodes + 63) / 64));
            spmm_w_lds_kernel<<<grid_w, dim3(1024), 0, stream>>>(
                off_f, ec0, W, (__half2*)filtered, n_nodes, in_ch);
        } else {
            spmm_csr_kernel<false, true, false><<<grid_r, block256, 0, stream>>>(
                off_f,  ec0, (const void*)W, (void*)filtered, n_nodes);
        }
        // stage 2: src fp16 filtered, dst fp16 tmp
        spmm_csr_kernel<true, true, false><<<grid_r, block256, 0, stream>>>(
            off_pi, ec1, (const void*)filtered, (void*)tmp, n_nodes);
        // stage 3: src fp16 tmp, dst fp32 out + relu
        spmm_csr_kernel<true, false, true><<<grid_r, block256, 0, stream>>>(
            off_p,  ec2, (const void*)tmp, d_out, n_nodes);
    } else {
        // fallback: round-0 atomic path (needs only 2 fp32 dense buffers)
        float* filtered = (float*)ws;
        float* tmp      = filtered + dense_elems;
        hipMemsetAsync(filtered, 0, 2 * dense_elems * sizeof(float), stream);
        hipMemsetAsync(d_out, 0, (size_t)out_size * sizeof(float), stream);
        {
            long long t = (long long)nnz_feat * OUT_CH;
            spmm_atomic_kernel<<<dim3((unsigned)((t + 255) / 256)), block256, 0, stream>>>(
                feat_idx, feat_idx + nnz_feat, feat_vals, nullptr, W, filtered, nnz_feat);
        }
        {
            long long t = (long long)nnz_phii * OUT_CH;
            spmm_atomic_kernel<<<dim3((unsigned)((t + 255) / 256)), block256, 0, stream>>>(
                phii_idx, phii_idx + nnz_phii, phii_vals, nullptr, filtered, tmp, nnz_phii);
        }
        {
            long long t = (long long)nnz_phi * OUT_CH;
            spmm_atomic_kernel<<<dim3((unsigned)((t + 255) / 256)), block256, 0, stream>>>(
                phi_idx, phi_idx + nnz_phi, phi_vals, theta, tmp, (float*)d_out, nnz_phi);
        }
        {
            int n4 = out_size / 4;
            relu_kernel<<<dim3((n4 + 255) / 256), block256, 0, stream>>>((float*)d_out, n4);
        }
    }
}

// Round 12
// 205.942 us; speedup vs baseline: 1.7648x; 1.7648x over previous
//
#include <hip/hip_runtime.h>
#include <hip/hip_fp16.h>

// SparseGraphWaveletLayer: out = relu( (phi·diag(theta)) @ (phi_inv @ (F_sparse @ W)) )
// N=50000, IN_CH=256, OUT_CH=128, NNZ=800000 per sparse matrix.
//
// Round 24 resubmit (round-24 bench was an infra failure: container died
// twice; source unchanged). This is the round-21 configuration (best
// measured: 206.2us): scalar edge loads (wave-uniform index -> s_load/SGPR
// path with 16 gathers in flight), W-in-LDS stage 1, register-staged D,
// 512-thread preprocessing, unroll-16 SpMM.

#define OUT_CH 128
#define HALF_CH 64
#define RPB 256           // rows per bucket
#define RPB_SHIFT 8
#define MAX_NB 256        // supports N <= 65536
#define EPB 4096          // edges per block in phases A/C
#define EPT_C 8           // edges per thread in phase C (512 thr)
#define EPT_D 16          // edges per thread in phase D (512 thr x 16 = 8192)
#define STAGE_CAP 8192    // phase-D LDS staging capacity (32KB of u32)
#define MAX_INCH_LDS 256  // W-in-LDS guard: in_ch*64 half2 <= 64KB

// ---------------- Phase A: per-block bucket histograms ----------------------

__global__ __launch_bounds__(512) void bucket_hist_kernel(
    const int* __restrict__ rows0, int n0,
    const int* __restrict__ rows1, int n1,
    const int* __restrict__ rows2, int n2,
    int* __restrict__ hist_part,        // [3][NBLK][NB]
    int NB, int NBLK)
{
    int m = blockIdx.y;
    const int* rows = (m == 0) ? rows0 : (m == 1) ? rows1 : rows2;
    int nnz         = (m == 0) ? n0    : (m == 1) ? n1    : n2;
    __shared__ int bins[MAX_NB];
    int t = threadIdx.x;
    if (t < NB) bins[t] = 0;
    __syncthreads();
    int base = blockIdx.x * EPB;
    #pragma unroll
    for (int k = 0; k < EPB / 512; ++k) {
        int i = base + k * 512 + t;
        if (i < nnz) atomicAdd(&bins[rows[i] >> RPB_SHIFT], 1);
    }
    __syncthreads();
    int* out = hist_part + ((size_t)(m * NBLK + blockIdx.x)) * NB;
    if (t < NB) out[t] = bins[t];
}

// ---------------- Phase B1: wave-per-(m,bucket) totals reduction ------------

__global__ __launch_bounds__(256) void reduce_totals_kernel(
    const int* __restrict__ hist_part, int* __restrict__ totals, int NB, int NBLK)
{
    int w = blockIdx.x * 4 + (threadIdx.x >> 6);
    if (w >= 3 * NB) return;
    int lane = threadIdx.x & 63;
    int m = w / NB, b = w - m * NB;
    const int* hp = hist_part + (size_t)m * NBLK * NB + b;
    int sum = 0;
    for (int blk = lane; blk < NBLK; blk += 64)
        sum += hp[(size_t)blk * NB];
    #pragma unroll
    for (int s = 1; s < 64; s <<= 1) sum += __shfl_xor(sum, s);
    if (lane == 0) totals[w] = sum;
}

// ---------------- Phase B2: scan totals -> bases + cursors ------------------

__global__ __launch_bounds__(256) void scan_bases_kernel(
    const int* __restrict__ totals, int* __restrict__ bases,
    int* __restrict__ cursor, int NB)
{
    int m = blockIdx.x, t = threadIdx.x;
    int x = (t < NB) ? totals[m * NB + t] : 0;
    int lane = t & 63, wid = t >> 6;
    int incl = x;
    #pragma unroll
    for (int s = 1; s < 64; s <<= 1) {
        int y = __shfl_up(incl, s);
        if (lane >= s) incl += y;
    }
    __shared__ int wtot[4], wbase[4];
    if (lane == 63) wtot[wid] = incl;
    __syncthreads();
    if (t == 0) {
        int run = 0;
        #pragma unroll
        for (int w = 0; w < 4; ++w) { int v = wtot[w]; wbase[w] = run; run += v; }
    }
    __syncthreads();
    if (t < NB) {
        int excl = wbase[wid] + incl - x;
        bases[m * NB + t] = excl;
        cursor[m * NB + t] = excl;
    }
}

// ---------------- Phase C: LDS-staged bucket scatter (chunk-claiming) -------

__global__ __launch_bounds__(512) void bucket_scatter_kernel(
    const int* __restrict__ rows0, const int* __restrict__ cols0, const float* __restrict__ vals0, int n0,
    const int* __restrict__ rows1, const int* __restrict__ cols1, const float* __restrict__ vals1, int n1,
    const int* __restrict__ rows2, const int* __restrict__ cols2, const float* __restrict__ vals2, int n2,
    const float* __restrict__ theta,
    const int* __restrict__ hist_part, int* __restrict__ cursor,
    int2* __restrict__ eb0, int2* __restrict__ eb1, int2* __restrict__ eb2,
    int NB, int NBLK)
{
    int m = blockIdx.y;
    const int* rows; const int* cols; const float* vals; int nnz; int2* eb;
    if (m == 0)      { rows = rows0; cols = cols0; vals = vals0; nnz = n0; eb = eb0; }
    else if (m == 1) { rows = rows1; cols = cols1; vals = vals1; nnz = n1; eb = eb1; }
    else             { rows = rows2; cols = cols2; vals = vals2; nnz = n2; eb = eb2; }

    __shared__ int2 staged[EPB];               // 32 KB
    __shared__ unsigned char bucket_of[EPB];   // 4 KB
    __shared__ int lstart[MAX_NB];
    __shared__ int lcur[MAX_NB];
    __shared__ int gbase[MAX_NB];
    __shared__ int wtot[8], wbase[8];

    int t = threadIdx.x;
    int base = blockIdx.x * EPB;
    bool fold = (m == 2);

    // load edges into registers
    int  bk[EPT_C];
    int2 pl[EPT_C];
    #pragma unroll
    for (int k = 0; k < EPT_C; ++k) {
        int i = base + k * 512 + t;
        if (i < nnz) {
            int r = rows[i], c = cols[i];
            float v = vals[i];
            if (fold) v *= theta[c];
            bk[k] = r >> RPB_SHIFT;
            pl[k] = make_int2(c | ((r & (RPB - 1)) << 16), __float_as_int(v));
        } else bk[k] = -1;
    }

    {   // per-block histogram comes precomputed from phase A; 8-wave scan
        const int* hp = hist_part + ((size_t)(m * NBLK + blockIdx.x)) * NB;
        int lh = (t < NB) ? hp[t] : 0;
        int lane = t & 63, wid = t >> 6;
        int incl = lh;
        #pragma unroll
        for (int s = 1; s < 64; s <<= 1) {
            int y = __shfl_up(incl, s);
            if (lane >= s) incl += y;
        }
        if (lane == 63) wtot[wid] = incl;
        __syncthreads();
        if (t == 0) {
            int run = 0;
            #pragma unroll
            for (int w = 0; w < 8; ++w) { int v = wtot[w]; wbase[w] = run; run += v; }
        }
        __syncthreads();
        if (t < NB) {
            int excl = wbase[wid] + incl - lh;
            lstart[t] = excl;
            lcur[t]   = excl;
            // claim a contiguous chunk of the bucket's output range
            gbase[t] = atomicAdd(&cursor[m * NB + t], lh);
        }
    }
    __syncthreads();

    #pragma unroll
    for (int k = 0; k < EPT_C; ++k) {
        if (bk[k] >= 0) {
            int idx = atomicAdd(&lcur[bk[k]], 1);     // LDS atomic
            staged[idx] = pl[k];
            bucket_of[idx] = (unsigned char)bk[k];
        }
    }
    __syncthreads();

    int count = min(EPB, nnz - base);
    for (int i = t; i < count; i += 512) {
        int b = bucket_of[i];
        int dest = gbase[b] + (i - lstart[b]);
        eb[dest] = staged[i];
    }
}

// ---------------- Phase D: bucket -> row-sorted COMPRESSED CSR + off --------
// Register-staged: the whole bucket (<= 8192 = 512x16) is loaded from eb
// ONCE into registers, histogrammed from regs, scanned, scattered from regs
// into LDS, then written out sequentially coalesced. Oversized buckets fall
// back to the two-pass loop.

__global__ __launch_bounds__(512) void bucket_to_csr_kernel(
    const int2* __restrict__ eb0, const int2* __restrict__ eb1, const int2* __restrict__ eb2,
    unsigned int* __restrict__ ec0, unsigned int* __restrict__ ec1, unsigned int* __restrict__ ec2,
    const int* __restrict__ bases,
    int* __restrict__ off,              // [3][n+1]
    int n0, int n1, int n2, int NB, int n)
{
    int m = blockIdx.y;
    int b = blockIdx.x;
    const int2* eb; unsigned int* ec; int nnz;
    if (m == 0)      { eb = eb0; ec = ec0; nnz = n0; }
    else if (m == 1) { eb = eb1; ec = ec1; nnz = n1; }
    else             { eb = eb2; ec = ec2; nnz = n2; }
    int base = bases[m * NB + b];
    int end  = (b + 1 < NB) ? bases[m * NB + b + 1] : nnz;
    int cnt  = end - base;

    __shared__ unsigned int staged_c[STAGE_CAP];   // 32 KB
    __shared__ int hist[RPB];
    __shared__ int cur[RPB];
    __shared__ int loc[RPB + 1];
    __shared__ int wtot[4];
    __shared__ int wbase[4];
    int t = threadIdx.x;
    int lane = t & 63, wid = t >> 6;
    if (t < RPB) { hist[t] = 0; cur[t] = 0; }
    __syncthreads();

    bool fits = (cnt <= STAGE_CAP);

    // ---- pass 1: row histogram ----
    int2 er[EPT_D];
    int  rl[EPT_D];
    if (fits) {
        #pragma unroll
        for (int k = 0; k < EPT_D; ++k) {
            int i = base + k * 512 + t;
            if (i < end) {
                er[k] = eb[i];
                rl[k] = (er[k].x >> 16) & (RPB - 1);
                atomicAdd(&hist[rl[k]], 1);
            } else rl[k] = -1;
        }
    } else {
        for (int i = base + t; i < end; i += 512)
            atomicAdd(&hist[(eb[i].x >> 16) & (RPB - 1)], 1);
    }
    __syncthreads();

    {   // exclusive scan of 256 counts (first 4 waves produce)
        int x = (t < RPB) ? hist[t] : 0;
        int incl = x;
        #pragma unroll
        for (int s = 1; s < 64; s <<= 1) {
            int y = __shfl_up(incl, s);
            if (lane >= s) incl += y;
        }
        if (lane == 63 && wid < 4) wtot[wid] = incl;
        __syncthreads();
        if (t == 0) {
            int run = 0;
            #pragma unroll
            for (int w = 0; w < 4; ++w) { int v = wtot[w]; wbase[w] = run; run += v; }
        }
        __syncthreads();
        if (t < RPB) {
            loc[t] = wbase[wid] + incl - x;
            if (t == RPB - 1) loc[RPB] = wbase[3] + incl;
        }
    }
    __syncthreads();
    if (t < RPB) {
        int r = b * RPB + t;
        if (r <= n) off[(size_t)m * (n + 1) + r] = base + loc[t];
        if (b == NB - 1 && t == 0) off[(size_t)m * (n + 1) + n] = nnz;
    }

    // ---- pass 2: row-sorted scatter ----
    if (fits) {
        #pragma unroll
        for (int k = 0; k < EPT_D; ++k) {
            if (rl[k] >= 0) {
                int rk = atomicAdd(&cur[rl[k]], 1);   // LDS atomic
                unsigned short h = __half_as_ushort(__float2half_rn(__int_as_float(er[k].y)));
                staged_c[loc[rl[k]] + rk] = (unsigned int)(er[k].x & 0xFFFF) | ((unsigned int)h << 16);
            }
        }
        __syncthreads();
        for (int i = t; i < cnt; i += 512)
            ec[base + i] = staged_c[i];
    } else {
        for (int i = base + t; i < end; i += 512) {
            int2 e = eb[i];
            int r2 = (e.x >> 16) & (RPB - 1);
            int rk = atomicAdd(&cur[r2], 1);
            unsigned short h = __half_as_ushort(__float2half_rn(__int_as_float(e.y)));
            ec[base + loc[r2] + rk] = (unsigned int)(e.x & 0xFFFF) | ((unsigned int)h << 16);
        }
    }
}

// ---------------- stage-1 SpMM with W resident in LDS -----------------------

__global__ __launch_bounds__(1024) void spmm_w_lds_kernel(
    const int* __restrict__ off, const unsigned int* __restrict__ edges,
    const float* __restrict__ W, __half2* __restrict__ out,
    int nrows, int in_ch)
{
    __shared__ __half2 wlds[MAX_INCH_LDS * HALF_CH];   // 64 KB
    int t = threadIdx.x;
    {   // stage W -> LDS (fp32 -> fp16), coalesced float2 reads
        const float2* wf = (const float2*)W;
        int tot = in_ch * HALF_CH;
        for (int i = t; i < tot; i += 1024) {
            float2 f = wf[i];
            wlds[i] = __float22half2_rn(f);
        }
    }
    __syncthreads();

    int lane = t & 63, w = t >> 6;     // 16 waves
    #pragma unroll
    for (int k4 = 0; k4 < 4; ++k4) {
        int r = blockIdx.x * 64 + k4 * 16 + w;
        if (r >= nrows) continue;
        int j   = __builtin_amdgcn_readfirstlane(off[r]);
        int end = __builtin_amdgcn_readfirstlane(off[r + 1]);
        float2 a0 = make_float2(0.f, 0.f), a1 = make_float2(0.f, 0.f);

        for (; j + 16 <= end; j += 16) {
            unsigned int e[16];
            #pragma unroll
            for (int k = 0; k < 16; ++k) e[k] = edges[j + k];
            #pragma unroll
            for (int k = 0; k < 16; ++k) {
                float2 d = __half22float2(wlds[(e[k] & 0xFFFF) * HALF_CH + lane]);
                float v = __half2float(__ushort_as_half((unsigned short)(e[k] >> 16)));
                if (k & 1) { a1.x = fmaf(v, d.x, a1.x); a1.y = fmaf(v, d.y, a1.y); }
                else       { a0.x = fmaf(v, d.x, a0.x); a0.y = fmaf(v, d.y, a0.y); }
            }
        }
        for (; j + 4 <= end; j += 4) {
            unsigned int e[4];
            #pragma unroll
            for (int k = 0; k < 4; ++k) e[k] = edges[j + k];
            #pragma unroll
            for (int k = 0; k < 4; ++k) {
                float2 d = __half22float2(wlds[(e[k] & 0xFFFF) * HALF_CH + lane]);
                float v = __half2float(__ushort_as_half((unsigned short)(e[k] >> 16)));
                if (k & 1) { a1.x = fmaf(v, d.x, a1.x); a1.y = fmaf(v, d.y, a1.y); }
                else       { a0.x = fmaf(v, d.x, a0.x); a0.y = fmaf(v, d.y, a0.y); }
            }
        }
        for (; j < end; ++j) {
            unsigned int e0 = edges[j];
            float2 d = __half22float2(wlds[(e0 & 0xFFFF) * HALF_CH + lane]);
            float v0 = __half2float(__ushort_as_half((unsigned short)(e0 >> 16)));
            a0.x = fmaf(v0, d.x, a0.x); a0.y = fmaf(v0, d.y, a0.y);
        }
        float2 res = make_float2(a0.x + a1.x, a0.y + a1.y);
        out[(size_t)r * HALF_CH + lane] = __float22half2_rn(res);
    }
}

// ---------------- gather-side CSR SpMM, 4B compressed edges, unroll-16 ------

template<bool SRC_H, bool DST_H, bool RELU>
__global__ __launch_bounds__(256) void spmm_csr_kernel(
    const int* __restrict__ off, const unsigned int* __restrict__ edges,
    const void* __restrict__ dense_v, void* __restrict__ out_v, int nrows)
{
    int lane = threadIdx.x & 63;
    int r = blockIdx.x * 4 + (threadIdx.x >> 6);
    if (r >= nrows) return;
    int j   = __builtin_amdgcn_readfirstlane(off[r]);
    int end = __builtin_amdgcn_readfirstlane(off[r + 1]);
    const float2*  df = (const float2*)dense_v;
    const __half2* dh = (const __half2*)dense_v;

    float2 a0 = make_float2(0.f, 0.f), a1 = make_float2(0.f, 0.f);

    for (; j + 16 <= end; j += 16) {
        unsigned int e[16]; float2 d[16];
        #pragma unroll
        for (int k = 0; k < 16; ++k) e[k] = edges[j + k];
        #pragma unroll
        for (int k = 0; k < 16; ++k) {
            if (SRC_H) d[k] = __half22float2(dh[(size_t)(e[k] & 0xFFFF) * HALF_CH + lane]);
            else       d[k] = df[(size_t)(e[k] & 0xFFFF) * HALF_CH + lane];
        }
        #pragma unroll
        for (int k = 0; k < 16; ++k) {
            float v = __half2float(__ushort_as_half((unsigned short)(e[k] >> 16)));
            if (k & 1) { a1.x = fmaf(v, d[k].x, a1.x); a1.y = fmaf(v, d[k].y, a1.y); }
            else       { a0.x = fmaf(v, d[k].x, a0.x); a0.y = fmaf(v, d[k].y, a0.y); }
        }
    }
    for (; j + 8 <= end; j += 8) {
        unsigned int e[8]; float2 d[8];
        #pragma unroll
        for (int k = 0; k < 8; ++k) e[k] = edges[j + k];
        #pragma unroll
        for (int k = 0; k < 8; ++k) {
            if (SRC_H) d[k] = __half22float2(dh[(size_t)(e[k] & 0xFFFF) * HALF_CH + lane]);
            else       d[k] = df[(size_t)(e[k] & 0xFFFF) * HALF_CH + lane];
        }
        #pragma unroll
        for (int k = 0; k < 8; ++k) {
            float v = __half2float(__ushort_as_half((unsigned short)(e[k] >> 16)));
            if (k & 1) { a1.x = fmaf(v, d[k].x, a1.x); a1.y = fmaf(v, d[k].y, a1.y); }
            else       { a0.x = fmaf(v, d[k].x, a0.x); a0.y = fmaf(v, d[k].y, a0.y); }
        }
    }
    for (; j + 4 <= end; j += 4) {
        unsigned int e[4]; float2 d[4];
        #pragma unroll
        for (int k = 0; k < 4; ++k) e[k] = edges[j + k];
        #pragma unroll
        for (int k = 0; k < 4; ++k) {
            if (SRC_H) d[k] = __half22float2(dh[(size_t)(e[k] & 0xFFFF) * HALF_CH + lane]);
            else       d[k] = df[(size_t)(e[k] & 0xFFFF) * HALF_CH + lane];
        }
        #pragma unroll
        for (int k = 0; k < 4; ++k) {
            float v = __half2float(__ushort_as_half((unsigned short)(e[k] >> 16)));
            if (k & 1) { a1.x = fmaf(v, d[k].x, a1.x); a1.y = fmaf(v, d[k].y, a1.y); }
            else       { a0.x = fmaf(v, d[k].x, a0.x); a0.y = fmaf(v, d[k].y, a0.y); }
        }
    }
    for (; j < end; ++j) {
        unsigned int e0 = edges[j];
        float2 d0;
        if (SRC_H) d0 = __half22float2(dh[(size_t)(e0 & 0xFFFF) * HALF_CH + lane]);
        else       d0 = df[(size_t)(e0 & 0xFFFF) * HALF_CH + lane];
        float v0 = __half2float(__ushort_as_half((unsigned short)(e0 >> 16)));
        a0.x = fmaf(v0, d0.x, a0.x); a0.y = fmaf(v0, d0.y, a0.y);
    }
    float2 res = make_float2(a0.x + a1.x, a0.y + a1.y);
    if (RELU) { res.x = fmaxf(res.x, 0.f); res.y = fmaxf(res.y, 0.f); }
    if (DST_H) ((__half2*)out_v)[(size_t)r * HALF_CH + lane] = __float22half2_rn(res);
    else       ((float2*) out_v)[(size_t)r * HALF_CH + lane] = res;
}

// ---------------- fallback (round-0) atomic path ----------------

__global__ __launch_bounds__(256) void spmm_atomic_kernel(
    const int* __restrict__ rows, const int* __restrict__ cols,
    const float* __restrict__ vals, const float* __restrict__ theta,
    const float* __restrict__ dense, float* __restrict__ out, int nnz)
{
    int idx = blockIdx.x * blockDim.x + threadIdx.x;
    int e = idx >> 7;
    int f = idx & (OUT_CH - 1);
    if (e >= nnz) return;
    int r = rows[e];
    int c = cols[e];
    float v = vals[e];
    if (theta != nullptr) v *= theta[c];
    atomicAdd(&out[(size_t)r * OUT_CH + f], v * dense[(size_t)c * OUT_CH + f]);
}

__global__ __launch_bounds__(256) void relu_kernel(float* __restrict__ out, int n4)
{
    int i = blockIdx.x * blockDim.x + threadIdx.x;
    if (i >= n4) return;
    float4 v = ((float4*)out)[i];
    v.x = fmaxf(v.x, 0.f); v.y = fmaxf(v.y, 0.f);
    v.z = fmaxf(v.z, 0.f); v.w = fmaxf(v.w, 0.f);
    ((float4*)out)[i] = v;
}

// ---------------- launch ----------------

static inline size_t align16(size_t x) { return (x + 15) & ~(size_t)15; }

extern "C" void kernel_launch(void* const* d_in, const int* in_sizes, int n_in,
                              void* d_out, int out_size, void* d_ws, size_t ws_size,
                              hipStream_t stream)
{
    const int*   phi_idx   = (const int*)d_in[0];
    const float* phi_vals  = (const float*)d_in[1];
    const int*   phii_idx  = (const int*)d_in[2];
    const float* phii_vals = (const float*)d_in[3];
    const int*   feat_idx  = (const int*)d_in[4];
    const float* feat_vals = (const float*)d_in[5];
    const float* W         = (const float*)d_in[6];
    const float* theta     = (const float*)d_in[7];

    const int nnz_phi  = in_sizes[1];
    const int nnz_phii = in_sizes[3];
    const int nnz_feat = in_sizes[5];
    const int n_nodes  = in_sizes[7];
    const int in_ch    = in_sizes[6] / OUT_CH;
    const size_t dense_elems = (size_t)n_nodes * OUT_CH;
    const long long total_e = (long long)nnz_feat + nnz_phii + nnz_phi;

    const int NB = (n_nodes + RPB - 1) >> RPB_SHIFT;
    int max_nnz = nnz_feat > nnz_phii ? nnz_feat : nnz_phii;
    if (nnz_phi > max_nnz) max_nnz = nnz_phi;
    const int NBLK = (max_nnz + EPB - 1) / EPB;

    // ---- workspace layout ----
    size_t p = 0;
    size_t filtered_off = p; p += align16(dense_elems * sizeof(__half));
    size_t tmp_off      = p; p += align16(dense_elems * sizeof(__half));
    size_t off_off      = p; p += align16((size_t)3 * (n_nodes + 1) * sizeof(int));
    size_t hp_off       = p; p += align16((size_t)3 * NBLK * NB * sizeof(int));
    size_t tot_off      = p; p += align16((size_t)3 * NB * sizeof(int));
    size_t bas_off      = p; p += align16((size_t)3 * NB * sizeof(int));
    size_t cur_off      = p; p += align16((size_t)3 * NB * sizeof(int));
    size_t eb_off       = p; p += align16((size_t)total_e * sizeof(int2));
    size_t ec_off       = p; p += align16((size_t)total_e * sizeof(unsigned int));
    size_t need = p;

    char* ws = (char*)d_ws;
    dim3 block256(256);
    dim3 block512(512);

    bool fast_ok = (ws_size >= need) && (NB <= MAX_NB) && (n_nodes <= 65536) &&
                   (in_ch <= 65536);

    if (fast_ok) {
        __half* filtered = (__half*)(ws + filtered_off);
        __half* tmp      = (__half*)(ws + tmp_off);
        int* off_arr    = (int*)(ws + off_off);
        int* hist_part  = (int*)(ws + hp_off);
        int* totals     = (int*)(ws + tot_off);
        int* bases      = (int*)(ws + bas_off);
        int* cursor     = (int*)(ws + cur_off);
        int2* eb0 = (int2*)(ws + eb_off);
        int2* eb1 = eb0 + nnz_feat;
        int2* eb2 = eb1 + nnz_phii;
        unsigned int* ec0 = (unsigned int*)(ws + ec_off);
        unsigned int* ec1 = ec0 + nnz_feat;
        unsigned int* ec2 = ec1 + nnz_phii;

        const int* rows0 = feat_idx;  const int* cols0 = feat_idx + nnz_feat;
        const int* rows1 = phii_idx;  const int* cols1 = phii_idx + nnz_phii;
        const int* rows2 = phi_idx;   const int* cols2 = phi_idx  + nnz_phi;

        bucket_hist_kernel<<<dim3(NBLK, 3), block512, 0, stream>>>(
            rows0, nnz_feat, rows1, nnz_phii, rows2, nnz_phi,
            hist_part, NB, NBLK);

        int nwaves = 3 * NB;
        reduce_totals_kernel<<<dim3((nwaves + 3) / 4), block256, 0, stream>>>(
            hist_part, totals, NB, NBLK);

        scan_bases_kernel<<<dim3(3), block256, 0, stream>>>(
            totals, bases, cursor, NB);

        bucket_scatter_kernel<<<dim3(NBLK, 3), block512, 0, stream>>>(
            rows0, cols0, feat_vals, nnz_feat,
            rows1, cols1, phii_vals, nnz_phii,
            rows2, cols2, phi_vals,  nnz_phi,
            theta, hist_part, cursor, eb0, eb1, eb2, NB, NBLK);

        bucket_to_csr_kernel<<<dim3(NB, 3), block512, 0, stream>>>(
            eb0, eb1, eb2, ec0, ec1, ec2, bases, off_arr,
            nnz_feat, nnz_phii, nnz_phi, NB, n_nodes);

        int* off_f  = off_arr;
        int* off_pi = off_arr + (n_nodes + 1);
        int* off_p  = off_arr + 2 * (n_nodes + 1);

        dim3 grid_r((unsigned)((n_nodes + 3) / 4));
        // stage 1: src fp32 W (LDS-resident fp16), dst fp16 filtered
        if (in_ch <= MAX_INCH_LDS) {
            dim3 grid_w((unsigned)((n_nodes + 63) / 64));
            spmm_w_lds_kernel<<<grid_w, dim3(1024), 0, stream>>>(
                off_f, ec0, W, (__half2*)filtered, n_nodes, in_ch);
        } else {
            spmm_csr_kernel<false, true, false><<<grid_r, block256, 0, stream>>>(
                off_f,  ec0, (const void*)W, (void*)filtered, n_nodes);
        }
        // stage 2: src fp16 filtered, dst fp16 tmp
        spmm_csr_kernel<true, true, false><<<grid_r, block256, 0, stream>>>(
            off_pi, ec1, (const void*)filtered, (void*)tmp, n_nodes);
        // stage 3: src fp16 tmp, dst fp32 out + relu
        spmm_csr_kernel<true, false, true><<<grid_r, block256, 0, stream>>>(
            off_p,  ec2, (const void*)tmp, d_out, n_nodes);
    } else {
        // fallback: round-0 atomic path (needs only 2 fp32 dense buffers)
        float* filtered = (float*)ws;
        float* tmp      = filtered + dense_elems;
        hipMemsetAsync(filtered, 0, 2 * dense_elems * sizeof(float), stream);
        hipMemsetAsync(d_out, 0, (size_t)out_size * sizeof(float), stream);
        {
            long long t = (long long)nnz_feat * OUT_CH;
            spmm_atomic_kernel<<<dim3((unsigned)((t + 255) / 256)), block256, 0, stream>>>(
                feat_idx, feat_idx + nnz_feat, feat_vals, nullptr, W, filtered, nnz_feat);
        }
        {
            long long t = (long long)nnz_phii * OUT_CH;
            spmm_atomic_kernel<<<dim3((unsigned)((t + 255) / 256)), block256, 0, stream>>>(
                phii_idx, phii_idx + nnz_phii, phii_vals, nullptr, filtered, tmp, nnz_phii);
        }
        {
            long long t = (long long)nnz_phi * OUT_CH;
            spmm_atomic_kernel<<<dim3((unsigned)((t + 255) / 256)), block256, 0, stream>>>(
                phi_idx, phi_idx + nnz_phi, phi_vals, theta, tmp, (float*)d_out, nnz_phi);
        }
        {
            int n4 = out_size / 4;
            relu_kernel<<<dim3((n4 + 255) / 256), block256, 0, stream>>>((float*)d_out, n4);
        }
    }
}